// Round 10
// baseline (441.788 us; speedup 1.0000x reference)
//
#include <hip/hip_runtime.h>
#include <hip/hip_bf16.h>

#define NN 50000
#define TB 1024             // 16 waves/block -> 4 waves/SIMD with ONE block/CU
#define NBLK 256            // one block per CU
#define WPB 16              // waves per block
#define TSTRIDE (NBLK * WPB)
static constexpr float EPS = 1e-5f;

typedef __attribute__((ext_vector_type(8))) short short8;
typedef __attribute__((ext_vector_type(16))) float f32x16;
typedef unsigned int u32;

// LDS frag table (1 frag = 64 lanes * 16B = 1 KB). No bias K-slots.
#define OFF_G2 0    // 4 mt * 4 ks = 16
#define OFF_G3 16   // 2 * 8 = 16
#define OFF_F1 32   // 2 * 8 = 16
#define OFF_F2 48   // 4 * 4 = 16
#define OFF_W3 64   // 2 * 8 = 16
#define NFRAGS 80   // 80 KB, one block/CU

__device__ __forceinline__ u32 pkbf(float a, float b) {
  u32 lo = (u32)__builtin_bit_cast(unsigned short, __float2bfloat16(a));
  u32 hi = (u32)__builtin_bit_cast(unsigned short, __float2bfloat16(b));
  return lo | (hi << 16);
}
__device__ __forceinline__ f32x16 zero16() {
  f32x16 z;
#pragma unroll
  for (int i = 0; i < 16; ++i) z[i] = 0.f;
  return z;
}

// Stage A-frags (W^T) to LDS as bf16. Lane l: A[row=l&31][k=8*(l>>5)+j].
template <int IN, int OUT>
__device__ __forceinline__ void stage(const float* __restrict__ W,
                                      uint4* __restrict__ lds, int fragoff,
                                      float scale, int tid) {
  constexpr int KS = IN / 16, MT = OUT / 32;
  constexpr int ENT = MT * KS * 64;
  for (int e = tid; e < ENT; e += TB) {
    int lane = e & 63, f = e >> 6;
    int mt = f / KS, ks = f - mt * KS;
    int h = lane >> 5, och = mt * 32 + (lane & 31);
    int k0 = ks * 16 + h * 8;
    u32 d[4];
#pragma unroll
    for (int p = 0; p < 4; ++p)
      d[p] = pkbf(W[(k0 + 2 * p) * OUT + och] * scale,
                  W[(k0 + 2 * p + 1) * OUT + och] * scale);
    lds[(fragoff + f) * 64 + lane] = make_uint4(d[0], d[1], d[2], d[3]);
  }
}

__device__ __forceinline__ short8 rdfrag(const uint4* __restrict__ lds,
                                         int fragidx, int lane) {
  return __builtin_bit_cast(short8, lds[fragidx * 64 + lane]);
}

// f32 acc (D-layout: pt=lane&31, ch=(r&3)+8*(r>>2)+4h+32mt) -> B-frags (proven).
template <int NK>
__device__ __forceinline__ void to_bfr(const f32x16* acc, short8* bfr) {
#pragma unroll
  for (int t = 0; t < NK; ++t) {
    const int mt = t >> 1, q0 = (t & 1) * 8;
    u32 P0 = pkbf(acc[mt][q0 + 0], acc[mt][q0 + 1]);
    u32 P1 = pkbf(acc[mt][q0 + 2], acc[mt][q0 + 3]);
    u32 P2 = pkbf(acc[mt][q0 + 4], acc[mt][q0 + 5]);
    u32 P3 = pkbf(acc[mt][q0 + 6], acc[mt][q0 + 7]);
    auto s1 = __builtin_amdgcn_permlane32_swap((int)P0, (int)P2, false, false);
    auto s2 = __builtin_amdgcn_permlane32_swap((int)P1, (int)P3, false, false);
    bfr[t] = __builtin_bit_cast(
        short8, make_uint4((u32)s1[0], (u32)s2[0], (u32)s1[1], (u32)s2[1]));
  }
}

__device__ __forceinline__ void add_bias64(f32x16* acc,
                                           const float* __restrict__ bias,
                                           int lane) {
  const int h = (lane >> 5) & 1;
#pragma unroll
  for (int mt = 0; mt < 2; ++mt)
#pragma unroll
    for (int rq = 0; rq < 4; ++rq) {
      const float4 b4 = *(const float4*)(bias + 32 * mt + 8 * rq + 4 * h);
      acc[mt][4 * rq + 0] += b4.x;
      acc[mt][4 * rq + 1] += b4.y;
      acc[mt][4 * rq + 2] += b4.z;
      acc[mt][4 * rq + 3] += b4.w;
    }
}

// bias + LN(64) + leaky relu on acc[2] (f32, in-place)
__device__ __forceinline__ void bias_ln_act64(f32x16* acc,
                                              const float* __restrict__ bias,
                                              const float* __restrict__ gam,
                                              const float* __restrict__ bet,
                                              int lane) {
  const int h = (lane >> 5) & 1;
  float s = 0.f, q = 0.f;
#pragma unroll
  for (int mt = 0; mt < 2; ++mt)
#pragma unroll
    for (int rq = 0; rq < 4; ++rq) {
      const float4 b4 = *(const float4*)(bias + 32 * mt + 8 * rq + 4 * h);
      const float bb[4] = {b4.x, b4.y, b4.z, b4.w};
#pragma unroll
      for (int c = 0; c < 4; ++c) {
        float v = acc[mt][4 * rq + c] + bb[c];
        acc[mt][4 * rq + c] = v;
        s += v;
        q += v * v;
      }
    }
  s += __shfl_xor(s, 32);
  q += __shfl_xor(q, 32);
  const float mean = s * (1.f / 64.f);
  const float inv = rsqrtf(q * (1.f / 64.f) - mean * mean + EPS);
#pragma unroll
  for (int mt = 0; mt < 2; ++mt)
#pragma unroll
    for (int rq = 0; rq < 4; ++rq) {
      const float4 g4 = *(const float4*)(gam + 32 * mt + 8 * rq + 4 * h);
      const float4 c4 = *(const float4*)(bet + 32 * mt + 8 * rq + 4 * h);
      const float gg[4] = {g4.x, g4.y, g4.z, g4.w};
      const float cc[4] = {c4.x, c4.y, c4.z, c4.w};
#pragma unroll
      for (int c = 0; c < 4; ++c) {
        float y = (acc[mt][4 * rq + c] - mean) * inv * gg[c] + cc[c];
        acc[mt][4 * rq + c] = fmaxf(y, 0.2f * y);
      }
    }
}

// Fused: [64->128 matmul + bias + LN + lrelu] streamed into [128->64 matmul].
// Two-pass LN (pass 1 stats, discard acc; pass 2 recompute + stream).
// mt loops are RUNTIME (#pragma unroll 1): param addresses become
// loop-variant so LICM cannot hoist them, and the body stays small.
__device__ __forceinline__ void fused128(const short8* kin4,
                                         const float* __restrict__ bias,
                                         const float* __restrict__ gam,
                                         const float* __restrict__ bet,
                                         const uint4* __restrict__ lds,
                                         int inOff, int outOff, f32x16* accOut,
                                         int lane) {
  const int h = (lane >> 5) & 1;
  float s = 0.f, q = 0.f;
  // ---- pass 1: stats only ----
#pragma unroll 1
  for (int mt = 0; mt < 4; ++mt) {
    f32x16 acc = zero16();
#pragma unroll
    for (int ks = 0; ks < 4; ++ks)
      acc = __builtin_amdgcn_mfma_f32_32x32x16_bf16(
          rdfrag(lds, inOff + mt * 4 + ks, lane), kin4[ks], acc, 0, 0, 0);
#pragma unroll
    for (int rq = 0; rq < 4; ++rq) {
      const float4 b4 = *(const float4*)(bias + 32 * mt + 8 * rq + 4 * h);
      float v0 = acc[4 * rq + 0] + b4.x, v1 = acc[4 * rq + 1] + b4.y;
      float v2 = acc[4 * rq + 2] + b4.z, v3 = acc[4 * rq + 3] + b4.w;
      s += (v0 + v1) + (v2 + v3);
      q += (v0 * v0 + v1 * v1) + (v2 * v2 + v3 * v3);
    }
  }
  s += __shfl_xor(s, 32);
  q += __shfl_xor(q, 32);
  const float mean = s * (1.f / 128.f);
  const float inv = rsqrtf(q * (1.f / 128.f) - mean * mean + EPS);
  asm volatile("" ::: "memory");  // no load CSE between pass 1 and pass 2
  // ---- pass 2: recompute, LN, stream into OUT layer ----
  accOut[0] = zero16();
  accOut[1] = zero16();
#pragma unroll 1
  for (int mt = 0; mt < 4; ++mt) {
    f32x16 acc = zero16();
#pragma unroll
    for (int ks = 0; ks < 4; ++ks)
      acc = __builtin_amdgcn_mfma_f32_32x32x16_bf16(
          rdfrag(lds, inOff + mt * 4 + ks, lane), kin4[ks], acc, 0, 0, 0);
#pragma unroll
    for (int u = 0; u < 2; ++u) {
      // regs r=8u+i, i=0..7 -> ch = (i&3) + 16u + 8*(i>>2) + 4h + 32mt
      const int c0 = 32 * mt + 16 * u + 4 * h;
      const float4 ba4 = *(const float4*)(bias + c0);
      const float4 bb4 = *(const float4*)(bias + c0 + 8);
      const float4 ga4 = *(const float4*)(gam + c0);
      const float4 gb4 = *(const float4*)(gam + c0 + 8);
      const float4 ca4 = *(const float4*)(bet + c0);
      const float4 cb4 = *(const float4*)(bet + c0 + 8);
      const float BB[8] = {ba4.x, ba4.y, ba4.z, ba4.w, bb4.x, bb4.y, bb4.z, bb4.w};
      const float GG[8] = {ga4.x, ga4.y, ga4.z, ga4.w, gb4.x, gb4.y, gb4.z, gb4.w};
      const float CC[8] = {ca4.x, ca4.y, ca4.z, ca4.w, cb4.x, cb4.y, cb4.z, cb4.w};
      u32 P[4];
#pragma unroll
      for (int p = 0; p < 4; ++p) {
        float a = acc[8 * u + 2 * p] + BB[2 * p];
        float b = acc[8 * u + 2 * p + 1] + BB[2 * p + 1];
        a = (a - mean) * inv * GG[2 * p] + CC[2 * p];
        b = (b - mean) * inv * GG[2 * p + 1] + CC[2 * p + 1];
        a = fmaxf(a, 0.2f * a);
        b = fmaxf(b, 0.2f * b);
        P[p] = pkbf(a, b);
      }
      auto s1 = __builtin_amdgcn_permlane32_swap((int)P[0], (int)P[2], false, false);
      auto s2 = __builtin_amdgcn_permlane32_swap((int)P[1], (int)P[3], false, false);
      const short8 frag = __builtin_bit_cast(
          short8, make_uint4((u32)s1[0], (u32)s2[0], (u32)s1[1], (u32)s2[1]));
      const int t = 2 * mt + u;
      accOut[0] = __builtin_amdgcn_mfma_f32_32x32x16_bf16(
          rdfrag(lds, outOff + t, lane), frag, accOut[0], 0, 0, 0);
      accOut[1] = __builtin_amdgcn_mfma_f32_32x32x16_bf16(
          rdfrag(lds, outOff + 8 + t, lane), frag, accOut[1], 0, 0, 0);
    }
  }
}

extern "C" __global__ void __launch_bounds__(TB)
    __attribute__((amdgpu_waves_per_eu(4, 4)))  // exactly 4 waves/EU -> 128 VGPR budget
lfa_mfma(const float* __restrict__ pf, const float* __restrict__ geom,
         const int* __restrict__ nidx,
         const float* __restrict__ g_w1, const float* __restrict__ g_b1,
         const float* __restrict__ g_ls1, const float* __restrict__ g_lb1,
         const float* __restrict__ g_w2, const float* __restrict__ g_b2,
         const float* __restrict__ g_ls2, const float* __restrict__ g_lb2,
         const float* __restrict__ g_w3, const float* __restrict__ g_b3,
         const float* __restrict__ f_w1, const float* __restrict__ f_b1,
         const float* __restrict__ f_ls1, const float* __restrict__ f_lb1,
         const float* __restrict__ f_w2, const float* __restrict__ f_b2,
         const float* __restrict__ f_ls2, const float* __restrict__ f_lb2,
         const float* __restrict__ f_w3, const float* __restrict__ f_b3,
         float* __restrict__ out) {
  extern __shared__ uint4 lds[];
  const int tid = threadIdx.x;

  stage<64, 128>(g_w2, lds, OFF_G2, 1.f, tid);
  stage<128, 64>(g_w3, lds, OFF_G3, 1.f, tid);
  stage<128, 64>(f_w1, lds, OFF_F1, 1.f, tid);
  stage<64, 128>(f_w2, lds, OFF_F2, 1.f, tid);
  stage<128, 64>(f_w3, lds, OFF_W3, 1.f / 16.f, tid);  // fold mean over K
  __syncthreads();

  const int lane = tid & 63;
  const int w = tid >> 6;
  const int h = lane >> 5;
  const int p31 = lane & 31;

  // gL1 A-frags (4 -> 64, K padded to 16; no bias slot)
  short8 a1[2];
#pragma unroll
  for (int mt = 0; mt < 2; ++mt) {
    const int och = 32 * mt + p31;
    uint4 qq;
    qq.x = h ? 0u : pkbf(g_w1[0 * 64 + och], g_w1[1 * 64 + och]);
    qq.y = h ? 0u : pkbf(g_w1[2 * 64 + och], g_w1[3 * 64 + och]);
    qq.z = 0u;
    qq.w = 0u;
    a1[mt] = __builtin_bit_cast(short8, qq);
  }

  short8 kin4[4];

  for (int tile = blockIdx.x * WPB + w; tile < NN; tile += TSTRIDE) {
    asm volatile("" ::: "memory");  // forbid LICM of any in-loop load
    const int rrow = tile * 32 + p31;
    const int bb = tile / 25000;

    // ---- geom L1: 4 -> 64 ----
    const float4 g4 = *(const float4*)(geom + (size_t)rrow * 4);
    uint4 gq;
    gq.x = h ? 0u : pkbf(g4.x, g4.y);
    gq.y = h ? 0u : pkbf(g4.z, g4.w);
    gq.z = 0u;
    gq.w = 0u;
    const short8 gb = __builtin_bit_cast(short8, gq);
    f32x16 accA[2];
#pragma unroll
    for (int mt = 0; mt < 2; ++mt)
      accA[mt] =
          __builtin_amdgcn_mfma_f32_32x32x16_bf16(a1[mt], gb, zero16(), 0, 0, 0);
    bias_ln_act64(accA, g_b1, g_ls1, g_lb1, lane);
    to_bfr<4>(accA, kin4);

    // ---- geom L2 (64->128, LN, lrelu) fused-streamed into geom L3 (128->64) ----
    fused128(kin4, g_b2, g_ls2, g_lb2, lds, OFF_G2, OFF_G3, accA, lane);
    add_bias64(accA, g_b3, lane);
    to_bfr<4>(accA, kin4);  // concat ch 0..63 -> B-frags ks 0..3

    // ---- feat L1: 128 -> 64, split: kin4 half + streamed gather half ----
#pragma unroll
    for (int mt = 0; mt < 2; ++mt) {
      accA[mt] = zero16();
#pragma unroll
      for (int ks = 0; ks < 4; ++ks)
        accA[mt] = __builtin_amdgcn_mfma_f32_32x32x16_bf16(
            rdfrag(lds, OFF_F1 + mt * 8 + ks, lane), kin4[ks], accA[mt], 0, 0, 0);
    }
    {
      const int idx = nidx[rrow];
      const float* prow = pf + ((size_t)bb * NN + idx) * 64;
#pragma unroll
      for (int t = 0; t < 4; ++t) {
        const float4 x = *(const float4*)(prow + 16 * t + 8 * h);
        const float4 yv = *(const float4*)(prow + 16 * t + 8 * h + 4);
        const short8 frag = __builtin_bit_cast(
            short8, make_uint4(pkbf(x.x, x.y), pkbf(x.z, x.w), pkbf(yv.x, yv.y),
                               pkbf(yv.z, yv.w)));
        accA[0] = __builtin_amdgcn_mfma_f32_32x32x16_bf16(
            rdfrag(lds, OFF_F1 + 4 + t, lane), frag, accA[0], 0, 0, 0);
        accA[1] = __builtin_amdgcn_mfma_f32_32x32x16_bf16(
            rdfrag(lds, OFF_F1 + 12 + t, lane), frag, accA[1], 0, 0, 0);
      }
    }
    bias_ln_act64(accA, f_b1, f_ls1, f_lb1, lane);
    to_bfr<4>(accA, kin4);

    // ---- feat L2 (64->128, LN, lrelu) fused-streamed into final (128->64)/16 ----
    fused128(kin4, f_b2, f_ls2, f_lb2, lds, OFF_F2, OFF_W3, accA, lane);

    // ---- sum over the 16 k-columns; add f_b3 at store ----
#pragma unroll
    for (int mt = 0; mt < 2; ++mt)
#pragma unroll
      for (int r = 0; r < 16; ++r) {
        float v = accA[mt][r];
        v += __shfl_xor(v, 1);
        v += __shfl_xor(v, 2);
        v += __shfl_xor(v, 4);
        v += __shfl_xor(v, 8);
        accA[mt][r] = v;
      }
    if ((lane & 15) < 4) {
      const int c = lane & 15;
      const int bn = (lane >> 4) & 1;
      const size_t row = (size_t)tile * 2 + bn;
#pragma unroll
      for (int mt = 0; mt < 2; ++mt) {
        const float4 bq = *(const float4*)(f_b3 + 32 * mt + 8 * c + 4 * h);
        const float4 v =
            (c == 0) ? make_float4(accA[mt][0], accA[mt][1], accA[mt][2], accA[mt][3])
          : (c == 1) ? make_float4(accA[mt][4], accA[mt][5], accA[mt][6], accA[mt][7])
          : (c == 2) ? make_float4(accA[mt][8], accA[mt][9], accA[mt][10], accA[mt][11])
                     : make_float4(accA[mt][12], accA[mt][13], accA[mt][14], accA[mt][15]);
        *(float4*)(out + row * 64 + 32 * mt + 8 * c + 4 * h) =
            make_float4(v.x + bq.x, v.y + bq.y, v.z + bq.z, v.w + bq.w);
      }
    }
  }
}

extern "C" void kernel_launch(void* const* d_in, const int* in_sizes, int n_in,
                              void* d_out, int out_size, void* d_ws, size_t ws_size,
                              hipStream_t stream) {
  const float* pf = (const float*)d_in[0];
  const float* geom = (const float*)d_in[1];
  const int* nidx = (const int*)d_in[2];
  const float* g_w1 = (const float*)d_in[3];
  const float* g_b1 = (const float*)d_in[4];
  const float* g_ls1 = (const float*)d_in[5];
  const float* g_lb1 = (const float*)d_in[6];
  const float* g_w2 = (const float*)d_in[7];
  const float* g_b2 = (const float*)d_in[8];
  const float* g_ls2 = (const float*)d_in[9];
  const float* g_lb2 = (const float*)d_in[10];
  const float* g_w3 = (const float*)d_in[11];
  const float* g_b3 = (const float*)d_in[12];
  const float* f_w1 = (const float*)d_in[13];
  const float* f_b1 = (const float*)d_in[14];
  const float* f_ls1 = (const float*)d_in[15];
  const float* f_lb1 = (const float*)d_in[16];
  const float* f_w2 = (const float*)d_in[17];
  const float* f_b2 = (const float*)d_in[18];
  const float* f_ls2 = (const float*)d_in[19];
  const float* f_lb2 = (const float*)d_in[20];
  const float* f_w3 = (const float*)d_in[21];
  const float* f_b3 = (const float*)d_in[22];

  const int shmem = NFRAGS * 64 * 16;  // 81920 B
  lfa_mfma<<<NBLK, TB, shmem, stream>>>(
      pf, geom, nidx, g_w1, g_b1, g_ls1, g_lb1, g_w2, g_b2, g_ls2, g_lb2, g_w3,
      g_b3, f_w1, f_b1, f_ls1, f_lb1, f_w2, f_b2, f_ls2, f_lb2, f_w3, f_b3,
      (float*)d_out);
}

// Round 11
// 386.342 us; speedup vs baseline: 1.1435x; 1.1435x over previous
//
#include <hip/hip_runtime.h>
#include <hip/hip_bf16.h>

#define NN 50000
#define TB 512
#define NBLK 250
#define WPB 8
#define STR (NBLK * WPB)  // 2000 waves; pair stride 2*STR
static constexpr float EPS = 1e-5f;

typedef __attribute__((ext_vector_type(8))) short short8;
typedef __attribute__((ext_vector_type(16))) float f32x16;
typedef unsigned int u32;

// LDS frag table (1 frag = 64 lanes * 16B = 1 KB). No bias K-slots.
#define OFF_G2 0
#define OFF_G3 16
#define OFF_F1 32
#define OFF_F2 48
#define OFF_W3 64
#define NFRAGS 80  // 80 KB

__device__ __forceinline__ u32 pkbf(float a, float b) {
  u32 lo = (u32)__builtin_bit_cast(unsigned short, __float2bfloat16(a));
  u32 hi = (u32)__builtin_bit_cast(unsigned short, __float2bfloat16(b));
  return lo | (hi << 16);
}
__device__ __forceinline__ f32x16 zero16() {
  f32x16 z;
#pragma unroll
  for (int i = 0; i < 16; ++i) z[i] = 0.f;
  return z;
}
#define MFMA __builtin_amdgcn_mfma_f32_32x32x16_bf16

// Stage A-frags (W^T) to LDS as bf16. Lane l: A[row=l&31][k=8*(l>>5)+j].
template <int IN, int OUT>
__device__ __forceinline__ void stage(const float* __restrict__ W,
                                      uint4* __restrict__ lds, int fragoff,
                                      float scale, int tid) {
  constexpr int KS = IN / 16, MT = OUT / 32;
  constexpr int ENT = MT * KS * 64;
  for (int e = tid; e < ENT; e += TB) {
    int lane = e & 63, f = e >> 6;
    int mt = f / KS, ks = f - mt * KS;
    int h = lane >> 5, och = mt * 32 + (lane & 31);
    int k0 = ks * 16 + h * 8;
    u32 d[4];
#pragma unroll
    for (int p = 0; p < 4; ++p)
      d[p] = pkbf(W[(k0 + 2 * p) * OUT + och] * scale,
                  W[(k0 + 2 * p + 1) * OUT + och] * scale);
    lds[(fragoff + f) * 64 + lane] = make_uint4(d[0], d[1], d[2], d[3]);
  }
}

__device__ __forceinline__ short8 rdfrag(const uint4* __restrict__ lds,
                                         int fragidx, int lane) {
  return __builtin_bit_cast(short8, lds[fragidx * 64 + lane]);
}

// f32 acc (D-layout: pt=lane&31, ch=(r&3)+8*(r>>2)+4h+32mt) -> B-frags (proven).
template <int NK>
__device__ __forceinline__ void to_bfr(const f32x16* acc, short8* bfr) {
#pragma unroll
  for (int t = 0; t < NK; ++t) {
    const int mt = t >> 1, q0 = (t & 1) * 8;
    u32 P0 = pkbf(acc[mt][q0 + 0], acc[mt][q0 + 1]);
    u32 P1 = pkbf(acc[mt][q0 + 2], acc[mt][q0 + 3]);
    u32 P2 = pkbf(acc[mt][q0 + 4], acc[mt][q0 + 5]);
    u32 P3 = pkbf(acc[mt][q0 + 6], acc[mt][q0 + 7]);
    auto s1 = __builtin_amdgcn_permlane32_swap((int)P0, (int)P2, false, false);
    auto s2 = __builtin_amdgcn_permlane32_swap((int)P1, (int)P3, false, false);
    bfr[t] = __builtin_bit_cast(
        short8, make_uint4((u32)s1[0], (u32)s2[0], (u32)s1[1], (u32)s2[1]));
  }
}

// dual bias add on two 64-wide acc pairs (shared param loads)
__device__ __forceinline__ void add_bias64_dual(f32x16* A, f32x16* B,
                                                const float* __restrict__ bias,
                                                int lane) {
  const int h = (lane >> 5) & 1;
#pragma unroll
  for (int mt = 0; mt < 2; ++mt)
#pragma unroll
    for (int rq = 0; rq < 4; ++rq) {
      const float4 b4 = *(const float4*)(bias + 32 * mt + 8 * rq + 4 * h);
      const float bb[4] = {b4.x, b4.y, b4.z, b4.w};
#pragma unroll
      for (int c = 0; c < 4; ++c) {
        A[mt][4 * rq + c] += bb[c];
        B[mt][4 * rq + c] += bb[c];
      }
    }
}

// dual bias + LN(64) + lrelu (shared param loads, two independent stat chains)
__device__ __forceinline__ void bias_ln_act64_dual(
    f32x16* A, f32x16* B, const float* __restrict__ bias,
    const float* __restrict__ gam, const float* __restrict__ bet, int lane) {
  const int h = (lane >> 5) & 1;
  float sA = 0.f, qA = 0.f, sB = 0.f, qB = 0.f;
#pragma unroll
  for (int mt = 0; mt < 2; ++mt)
#pragma unroll
    for (int rq = 0; rq < 4; ++rq) {
      const float4 b4 = *(const float4*)(bias + 32 * mt + 8 * rq + 4 * h);
      const float bb[4] = {b4.x, b4.y, b4.z, b4.w};
#pragma unroll
      for (int c = 0; c < 4; ++c) {
        float va = A[mt][4 * rq + c] + bb[c];
        float vb = B[mt][4 * rq + c] + bb[c];
        A[mt][4 * rq + c] = va;
        B[mt][4 * rq + c] = vb;
        sA += va; qA += va * va;
        sB += vb; qB += vb * vb;
      }
    }
  sA += __shfl_xor(sA, 32); qA += __shfl_xor(qA, 32);
  sB += __shfl_xor(sB, 32); qB += __shfl_xor(qB, 32);
  const float mA = sA * (1.f / 64.f);
  const float iA = rsqrtf(qA * (1.f / 64.f) - mA * mA + EPS);
  const float mB = sB * (1.f / 64.f);
  const float iB = rsqrtf(qB * (1.f / 64.f) - mB * mB + EPS);
#pragma unroll
  for (int mt = 0; mt < 2; ++mt)
#pragma unroll
    for (int rq = 0; rq < 4; ++rq) {
      const float4 g4 = *(const float4*)(gam + 32 * mt + 8 * rq + 4 * h);
      const float4 c4 = *(const float4*)(bet + 32 * mt + 8 * rq + 4 * h);
      const float gg[4] = {g4.x, g4.y, g4.z, g4.w};
      const float cc[4] = {c4.x, c4.y, c4.z, c4.w};
#pragma unroll
      for (int c = 0; c < 4; ++c) {
        float ya = (A[mt][4 * rq + c] - mA) * iA * gg[c] + cc[c];
        float yb = (B[mt][4 * rq + c] - mB) * iB * gg[c] + cc[c];
        A[mt][4 * rq + c] = fmaxf(ya, 0.2f * ya);
        B[mt][4 * rq + c] = fmaxf(yb, 0.2f * yb);
      }
    }
}

// Dual fused [64->128 + bias + LN + lrelu] streamed into [128->64].
// Two-pass LN; weight frags and params loaded ONCE, used by both chains.
__device__ __forceinline__ void fused128_dual(
    const short8* kinA, const short8* kinB, const float* __restrict__ bias,
    const float* __restrict__ gam, const float* __restrict__ bet,
    const uint4* __restrict__ lds, int inOff, int outOff, f32x16* outA,
    f32x16* outB, int lane) {
  const int h = (lane >> 5) & 1;
  float sA = 0.f, qA = 0.f, sB = 0.f, qB = 0.f;
  // ---- pass 1: stats only ----
#pragma unroll 1
  for (int mt = 0; mt < 4; ++mt) {
    f32x16 a = zero16(), b = zero16();
#pragma unroll
    for (int ks = 0; ks < 4; ++ks) {
      const short8 wf = rdfrag(lds, inOff + mt * 4 + ks, lane);
      a = MFMA(wf, kinA[ks], a, 0, 0, 0);
      b = MFMA(wf, kinB[ks], b, 0, 0, 0);
    }
#pragma unroll
    for (int rq = 0; rq < 4; ++rq) {
      const float4 b4 = *(const float4*)(bias + 32 * mt + 8 * rq + 4 * h);
      const float bb[4] = {b4.x, b4.y, b4.z, b4.w};
#pragma unroll
      for (int c = 0; c < 4; ++c) {
        float va = a[4 * rq + c] + bb[c];
        float vb = b[4 * rq + c] + bb[c];
        sA += va; qA += va * va;
        sB += vb; qB += vb * vb;
      }
    }
  }
  sA += __shfl_xor(sA, 32); qA += __shfl_xor(qA, 32);
  sB += __shfl_xor(sB, 32); qB += __shfl_xor(qB, 32);
  const float mA = sA * (1.f / 128.f);
  const float iA = rsqrtf(qA * (1.f / 128.f) - mA * mA + EPS);
  const float mB = sB * (1.f / 128.f);
  const float iB = rsqrtf(qB * (1.f / 128.f) - mB * mB + EPS);
  asm volatile("" ::: "memory");  // no load CSE between pass 1 and pass 2
  // ---- pass 2: recompute, LN, stream into OUT layer ----
  outA[0] = zero16(); outA[1] = zero16();
  outB[0] = zero16(); outB[1] = zero16();
#pragma unroll 1
  for (int mt = 0; mt < 4; ++mt) {
    f32x16 a = zero16(), b = zero16();
#pragma unroll
    for (int ks = 0; ks < 4; ++ks) {
      const short8 wf = rdfrag(lds, inOff + mt * 4 + ks, lane);
      a = MFMA(wf, kinA[ks], a, 0, 0, 0);
      b = MFMA(wf, kinB[ks], b, 0, 0, 0);
    }
#pragma unroll
    for (int u = 0; u < 2; ++u) {
      const int c0 = 32 * mt + 16 * u + 4 * h;
      const float4 ba4 = *(const float4*)(bias + c0);
      const float4 bb4 = *(const float4*)(bias + c0 + 8);
      const float4 ga4 = *(const float4*)(gam + c0);
      const float4 gb4 = *(const float4*)(gam + c0 + 8);
      const float4 ca4 = *(const float4*)(bet + c0);
      const float4 cb4 = *(const float4*)(bet + c0 + 8);
      const float BB[8] = {ba4.x, ba4.y, ba4.z, ba4.w, bb4.x, bb4.y, bb4.z, bb4.w};
      const float GG[8] = {ga4.x, ga4.y, ga4.z, ga4.w, gb4.x, gb4.y, gb4.z, gb4.w};
      const float CC[8] = {ca4.x, ca4.y, ca4.z, ca4.w, cb4.x, cb4.y, cb4.z, cb4.w};
      u32 PA[4], PB[4];
#pragma unroll
      for (int p = 0; p < 4; ++p) {
        float a0 = (a[8 * u + 2 * p] + BB[2 * p] - mA) * iA * GG[2 * p] + CC[2 * p];
        float a1 = (a[8 * u + 2 * p + 1] + BB[2 * p + 1] - mA) * iA * GG[2 * p + 1] + CC[2 * p + 1];
        float b0 = (b[8 * u + 2 * p] + BB[2 * p] - mB) * iB * GG[2 * p] + CC[2 * p];
        float b1 = (b[8 * u + 2 * p + 1] + BB[2 * p + 1] - mB) * iB * GG[2 * p + 1] + CC[2 * p + 1];
        a0 = fmaxf(a0, 0.2f * a0); a1 = fmaxf(a1, 0.2f * a1);
        b0 = fmaxf(b0, 0.2f * b0); b1 = fmaxf(b1, 0.2f * b1);
        PA[p] = pkbf(a0, a1);
        PB[p] = pkbf(b0, b1);
      }
      auto sa1 = __builtin_amdgcn_permlane32_swap((int)PA[0], (int)PA[2], false, false);
      auto sa2 = __builtin_amdgcn_permlane32_swap((int)PA[1], (int)PA[3], false, false);
      auto sb1 = __builtin_amdgcn_permlane32_swap((int)PB[0], (int)PB[2], false, false);
      auto sb2 = __builtin_amdgcn_permlane32_swap((int)PB[1], (int)PB[3], false, false);
      const short8 frA = __builtin_bit_cast(
          short8, make_uint4((u32)sa1[0], (u32)sa2[0], (u32)sa1[1], (u32)sa2[1]));
      const short8 frB = __builtin_bit_cast(
          short8, make_uint4((u32)sb1[0], (u32)sb2[0], (u32)sb1[1], (u32)sb2[1]));
      const int t = 2 * mt + u;
      const short8 w0 = rdfrag(lds, outOff + t, lane);
      const short8 w1 = rdfrag(lds, outOff + 8 + t, lane);
      outA[0] = MFMA(w0, frA, outA[0], 0, 0, 0);
      outA[1] = MFMA(w1, frA, outA[1], 0, 0, 0);
      outB[0] = MFMA(w0, frB, outB[0], 0, 0, 0);
      outB[1] = MFMA(w1, frB, outB[1], 0, 0, 0);
    }
  }
}

extern "C" __global__ void __launch_bounds__(TB)
    __attribute__((amdgpu_waves_per_eu(2, 2)))  // 2 waves/EU -> 256-VGPR budget
lfa_mfma(const float* __restrict__ pf, const float* __restrict__ geom,
         const int* __restrict__ nidx,
         const float* __restrict__ g_w1, const float* __restrict__ g_b1,
         const float* __restrict__ g_ls1, const float* __restrict__ g_lb1,
         const float* __restrict__ g_w2, const float* __restrict__ g_b2,
         const float* __restrict__ g_ls2, const float* __restrict__ g_lb2,
         const float* __restrict__ g_w3, const float* __restrict__ g_b3,
         const float* __restrict__ f_w1, const float* __restrict__ f_b1,
         const float* __restrict__ f_ls1, const float* __restrict__ f_lb1,
         const float* __restrict__ f_w2, const float* __restrict__ f_b2,
         const float* __restrict__ f_ls2, const float* __restrict__ f_lb2,
         const float* __restrict__ f_w3, const float* __restrict__ f_b3,
         float* __restrict__ out) {
  extern __shared__ uint4 lds[];
  const int tid = threadIdx.x;

  stage<64, 128>(g_w2, lds, OFF_G2, 1.f, tid);
  stage<128, 64>(g_w3, lds, OFF_G3, 1.f, tid);
  stage<128, 64>(f_w1, lds, OFF_F1, 1.f, tid);
  stage<64, 128>(f_w2, lds, OFF_F2, 1.f, tid);
  stage<128, 64>(f_w3, lds, OFF_W3, 1.f / 16.f, tid);  // fold mean over K
  __syncthreads();

  const int lane = tid & 63;
  const int w = tid >> 6;
  const int h = lane >> 5;
  const int p31 = lane & 31;

  // gL1 A-frags (4 -> 64, K padded to 16)
  short8 a1[2];
#pragma unroll
  for (int mt = 0; mt < 2; ++mt) {
    const int och = 32 * mt + p31;
    uint4 qq;
    qq.x = h ? 0u : pkbf(g_w1[0 * 64 + och], g_w1[1 * 64 + och]);
    qq.y = h ? 0u : pkbf(g_w1[2 * 64 + och], g_w1[3 * 64 + och]);
    qq.z = 0u;
    qq.w = 0u;
    a1[mt] = __builtin_bit_cast(short8, qq);
  }

  short8 kinA[4], kinB[4];

  for (int t0 = blockIdx.x * WPB + w; t0 < NN; t0 += 2 * STR) {
    asm volatile("" ::: "memory");  // forbid LICM of any in-loop load
    const int tileA = t0;
    const bool hasB = (t0 + STR) < NN;           // wave-uniform
    const int tileB = hasB ? (t0 + STR) : tileA;  // redundant compute on tail
    const int rrowA = tileA * 32 + p31;
    const int rrowB = tileB * 32 + p31;
    const int bbA = tileA / 25000;
    const int bbB = tileB / 25000;

    // ---- geom L1: 4 -> 64 (dual) ----
    const float4 gA = *(const float4*)(geom + (size_t)rrowA * 4);
    const float4 gB = *(const float4*)(geom + (size_t)rrowB * 4);
    uint4 qA, qB;
    qA.x = h ? 0u : pkbf(gA.x, gA.y);
    qA.y = h ? 0u : pkbf(gA.z, gA.w);
    qA.z = 0u; qA.w = 0u;
    qB.x = h ? 0u : pkbf(gB.x, gB.y);
    qB.y = h ? 0u : pkbf(gB.z, gB.w);
    qB.z = 0u; qB.w = 0u;
    const short8 gfA = __builtin_bit_cast(short8, qA);
    const short8 gfB = __builtin_bit_cast(short8, qB);
    f32x16 accA[2], accB[2];
#pragma unroll
    for (int mt = 0; mt < 2; ++mt) {
      accA[mt] = MFMA(a1[mt], gfA, zero16(), 0, 0, 0);
      accB[mt] = MFMA(a1[mt], gfB, zero16(), 0, 0, 0);
    }
    bias_ln_act64_dual(accA, accB, g_b1, g_ls1, g_lb1, lane);
    to_bfr<4>(accA, kinA);
    to_bfr<4>(accB, kinB);

    // ---- geom L2 -> geom L3 (dual fused) ----
    fused128_dual(kinA, kinB, g_b2, g_ls2, g_lb2, lds, OFF_G2, OFF_G3, accA,
                  accB, lane);
    add_bias64_dual(accA, accB, g_b3, lane);
    to_bfr<4>(accA, kinA);
    to_bfr<4>(accB, kinB);

    // ---- feat L1: 128 -> 64 (dual; first half from kin, gather streamed) ----
#pragma unroll
    for (int mt = 0; mt < 2; ++mt) {
      f32x16 ta = zero16(), tb = zero16();
#pragma unroll
      for (int ks = 0; ks < 4; ++ks) {
        const short8 wf = rdfrag(lds, OFF_F1 + mt * 8 + ks, lane);
        ta = MFMA(wf, kinA[ks], ta, 0, 0, 0);
        tb = MFMA(wf, kinB[ks], tb, 0, 0, 0);
      }
      accA[mt] = ta;
      accB[mt] = tb;
    }
    {
      const int idxA = nidx[rrowA];
      const int idxB = nidx[rrowB];
      const float* prA = pf + ((size_t)bbA * NN + idxA) * 64;
      const float* prB = pf + ((size_t)bbB * NN + idxB) * 64;
#pragma unroll
      for (int t = 0; t < 4; ++t) {
        const float4 xA = *(const float4*)(prA + 16 * t + 8 * h);
        const float4 yA = *(const float4*)(prA + 16 * t + 8 * h + 4);
        const float4 xB = *(const float4*)(prB + 16 * t + 8 * h);
        const float4 yB = *(const float4*)(prB + 16 * t + 8 * h + 4);
        const short8 fA = __builtin_bit_cast(
            short8, make_uint4(pkbf(xA.x, xA.y), pkbf(xA.z, xA.w),
                               pkbf(yA.x, yA.y), pkbf(yA.z, yA.w)));
        const short8 fB = __builtin_bit_cast(
            short8, make_uint4(pkbf(xB.x, xB.y), pkbf(xB.z, xB.w),
                               pkbf(yB.x, yB.y), pkbf(yB.z, yB.w)));
        const short8 w0 = rdfrag(lds, OFF_F1 + 4 + t, lane);
        const short8 w1 = rdfrag(lds, OFF_F1 + 12 + t, lane);
        accA[0] = MFMA(w0, fA, accA[0], 0, 0, 0);
        accA[1] = MFMA(w1, fA, accA[1], 0, 0, 0);
        accB[0] = MFMA(w0, fB, accB[0], 0, 0, 0);
        accB[1] = MFMA(w1, fB, accB[1], 0, 0, 0);
      }
    }
    bias_ln_act64_dual(accA, accB, f_b1, f_ls1, f_lb1, lane);
    to_bfr<4>(accA, kinA);
    to_bfr<4>(accB, kinB);

    // ---- feat L2 -> final/16 (dual fused) ----
    fused128_dual(kinA, kinB, f_b2, f_ls2, f_lb2, lds, OFF_F2, OFF_W3, accA,
                  accB, lane);

    // ---- sum over 16 k-columns (both), add f_b3 at store ----
#pragma unroll
    for (int mt = 0; mt < 2; ++mt)
#pragma unroll
      for (int r = 0; r < 16; ++r) {
        float va = accA[mt][r];
        float vb = accB[mt][r];
        va += __shfl_xor(va, 1); vb += __shfl_xor(vb, 1);
        va += __shfl_xor(va, 2); vb += __shfl_xor(vb, 2);
        va += __shfl_xor(va, 4); vb += __shfl_xor(vb, 4);
        va += __shfl_xor(va, 8); vb += __shfl_xor(vb, 8);
        accA[mt][r] = va;
        accB[mt][r] = vb;
      }
    if ((lane & 15) < 4) {
      const int c = lane & 15;
      const int bn = (lane >> 4) & 1;
      const size_t rowA = (size_t)tileA * 2 + bn;
      const size_t rowB = (size_t)tileB * 2 + bn;
#pragma unroll
      for (int mt = 0; mt < 2; ++mt) {
        const float4 bq = *(const float4*)(f_b3 + 32 * mt + 8 * c + 4 * h);
        const float4 vA =
            (c == 0) ? make_float4(accA[mt][0], accA[mt][1], accA[mt][2], accA[mt][3])
          : (c == 1) ? make_float4(accA[mt][4], accA[mt][5], accA[mt][6], accA[mt][7])
          : (c == 2) ? make_float4(accA[mt][8], accA[mt][9], accA[mt][10], accA[mt][11])
                     : make_float4(accA[mt][12], accA[mt][13], accA[mt][14], accA[mt][15]);
        *(float4*)(out + rowA * 64 + 32 * mt + 8 * c + 4 * h) =
            make_float4(vA.x + bq.x, vA.y + bq.y, vA.z + bq.z, vA.w + bq.w);
        if (hasB) {
          const float4 vB =
              (c == 0) ? make_float4(accB[mt][0], accB[mt][1], accB[mt][2], accB[mt][3])
            : (c == 1) ? make_float4(accB[mt][4], accB[mt][5], accB[mt][6], accB[mt][7])
            : (c == 2) ? make_float4(accB[mt][8], accB[mt][9], accB[mt][10], accB[mt][11])
                       : make_float4(accB[mt][12], accB[mt][13], accB[mt][14], accB[mt][15]);
          *(float4*)(out + rowB * 64 + 32 * mt + 8 * c + 4 * h) =
              make_float4(vB.x + bq.x, vB.y + bq.y, vB.z + bq.z, vB.w + bq.w);
        }
      }
    }
  }
}

extern "C" void kernel_launch(void* const* d_in, const int* in_sizes, int n_in,
                              void* d_out, int out_size, void* d_ws, size_t ws_size,
                              hipStream_t stream) {
  const float* pf = (const float*)d_in[0];
  const float* geom = (const float*)d_in[1];
  const int* nidx = (const int*)d_in[2];
  const float* g_w1 = (const float*)d_in[3];
  const float* g_b1 = (const float*)d_in[4];
  const float* g_ls1 = (const float*)d_in[5];
  const float* g_lb1 = (const float*)d_in[6];
  const float* g_w2 = (const float*)d_in[7];
  const float* g_b2 = (const float*)d_in[8];
  const float* g_ls2 = (const float*)d_in[9];
  const float* g_lb2 = (const float*)d_in[10];
  const float* g_w3 = (const float*)d_in[11];
  const float* g_b3 = (const float*)d_in[12];
  const float* f_w1 = (const float*)d_in[13];
  const float* f_b1 = (const float*)d_in[14];
  const float* f_ls1 = (const float*)d_in[15];
  const float* f_lb1 = (const float*)d_in[16];
  const float* f_w2 = (const float*)d_in[17];
  const float* f_b2 = (const float*)d_in[18];
  const float* f_ls2 = (const float*)d_in[19];
  const float* f_lb2 = (const float*)d_in[20];
  const float* f_w3 = (const float*)d_in[21];
  const float* f_b3 = (const float*)d_in[22];

  const int shmem = NFRAGS * 64 * 16;  // 81920 B
  lfa_mfma<<<NBLK, TB, shmem, stream>>>(
      pf, geom, nidx, g_w1, g_b1, g_ls1, g_lb1, g_w2, g_b2, g_ls2, g_lb2, g_w3,
      g_b3, f_w1, f_b1, f_ls1, f_lb1, f_w2, f_b2, f_ls2, f_lb2, f_w3, f_b3,
      (float*)d_out);
}